// Round 1
// baseline (634.062 us; speedup 1.0000x reference)
//
#include <hip/hip_runtime.h>

typedef unsigned short u16;
typedef u16    u16x4  __attribute__((ext_vector_type(4)));
typedef u16    u16x8  __attribute__((ext_vector_type(8)));
typedef __bf16 bf16x8 __attribute__((ext_vector_type(8)));
typedef float  f32x4  __attribute__((ext_vector_type(4)));
typedef float  f32x16 __attribute__((ext_vector_type(16)));

#define DEV static __device__ __forceinline__

DEV float bf2f(u16 h) {
    union { unsigned int u; float f; } c; c.u = ((unsigned int)h) << 16; return c.f;
}
DEV u16 f2bf(float f) {
    union { float f; unsigned int u; } c; c.f = f;
    unsigned int u = c.u + 0x7FFFu + ((c.u >> 16) & 1u);
    return (u16)(u >> 16);
}
DEV bf16x8 ld8(const u16* p) {
    return __builtin_bit_cast(bf16x8, *(const u16x8*)p);
}
DEV void gload_lds16(const u16* g, u16* l) {
    __builtin_amdgcn_global_load_lds((__attribute__((address_space(1))) void*)g,
                                     (__attribute__((address_space(3))) void*)l,
                                     16, 0, 0);
}

// ---------------------------------------------------------------------------
// f32 -> bf16 elementwise convert (n multiple of 4).
// ---------------------------------------------------------------------------
__global__ __launch_bounds__(256) void f32_to_bf16(
    const float* __restrict__ src, u16* __restrict__ dst, int n)
{
    int i = (blockIdx.x * 256 + threadIdx.x) * 4;
    if (i < n) {
        f32x4 v = *(const f32x4*)(src + i);
        u16x4 o;
        o[0] = f2bf(v[0]); o[1] = f2bf(v[1]); o[2] = f2bf(v[2]); o[3] = f2bf(v[3]);
        *(u16x4*)(dst + i) = o;
    }
}

// ---------------------------------------------------------------------------
// Prep: de-interleave conv weights [O][I][KS] -> [tap][O][I] (bf16), fold BN
// scale (and 0.125 attention scale into Q weights). f32 inputs.
// ---------------------------------------------------------------------------
__global__ __launch_bounds__(256) void prep_weights(
    const float* __restrict__ Wq, const float* __restrict__ gq, const float* __restrict__ vq,
    const float* __restrict__ Wk, const float* __restrict__ gk, const float* __restrict__ vk,
    u16* __restrict__ Wqt, u16* __restrict__ Wkt)
{
    int idx = blockIdx.x * 256 + threadIdx.x;        // 0 .. 2*786432-1
    int mat = idx >= 786432;                         // 0=q, 1=k
    int rem = idx - mat * 786432;
    int tap = rem / 262144;
    int oi  = rem - tap * 262144;
    int o = oi >> 9, i = oi & 511;
    const float* W = mat ? Wk : Wq;
    const float* g = mat ? gk : gq;
    const float* v = mat ? vk : vq;
    float s = g[o] * rsqrtf(v[o] + 1e-5f) * (mat ? 1.0f : 0.125f);
    float w = W[(o * 512 + i) * 3 + tap] * s;
    (mat ? Wkt : Wqt)[(tap * 512 + o) * 512 + i] = f2bf(w);
}

__global__ __launch_bounds__(256) void prep_bias(
    const float* bq, const float* gq, const float* betaq, const float* mq, const float* vq,
    const float* bk, const float* gk, const float* betak, const float* mk, const float* vk,
    float* __restrict__ biasq, float* __restrict__ biask)
{
    int o = blockIdx.x * 256 + threadIdx.x;
    if (o < 512) {
        float sq = gq[o] * rsqrtf(vq[o] + 1e-5f);
        biasq[o] = ((bq[o] - mq[o]) * sq + betaq[o]) * 0.125f;
        float sk = gk[o] * rsqrtf(vk[o] + 1e-5f);
        biask[o] = (bk[o] - mk[o]) * sk + betak[o];
    }
}

// ---------------------------------------------------------------------------
// K1: fused QKV. Grid (12, 64*NB). blockIdx.x: [0,4)=Q cols, [4,8)=K, [8,12)=V.
// blockIdx.y = (brel,t). GEMM rows = 128 vertices n. Q/K accumulate 3 taps
// with t-shifted Xb row-tiles (causal conv). Xb indexed by absolute b.
// Output layout: [brel][n][h][t][dh] (bf16).
//
// Round-4 structure: BK=64 (half the barrier drains of BK=32),
// v_mfma_f32_32x32x16_bf16 (half the MFMA instruction count, -17% matrix-pipe
// issue cycles), and an XOR bank-swizzle on the [128][64] bf16 LDS tiles.
// Swizzle (rule #21, both-sides): LDS 16B-slot bits [4:6] of the byte offset
// are XORed with row&7 (bits [7:9]). gload_lds writes LINEAR LDS; the global
// SOURCE address is pre-swizzled (involution), and ds_read applies the same
// XOR. Fragment reads (32 lanes x stride-128B rows) drop from 32-way to
// 4-way conflict.
// ---------------------------------------------------------------------------
__global__ __launch_bounds__(256) void qkv_gemm(
    const u16* __restrict__ Xb,
    const u16* __restrict__ Wqt, const u16* __restrict__ Wkt, const u16* __restrict__ Wv,
    const float* __restrict__ biasq, const float* __restrict__ biask, const float* __restrict__ bv,
    u16* __restrict__ Qa, u16* __restrict__ Ka, u16* __restrict__ Va, int b0)
{
    __shared__ __align__(16) u16 As[128 * 64];
    __shared__ __align__(16) u16 Bs[128 * 64];

    const int which = blockIdx.x >> 2;            // 0=q 1=k 2=v
    const int cb    = (blockIdx.x & 3) * 128;
    const int rt    = blockIdx.y;
    const int brel  = rt >> 6;
    const int b     = b0 + brel;
    const int t     = rt & 63;

    const int tid  = threadIdx.x;
    const int wave = tid >> 6;
    const int lane = tid & 63;
    const int wm   = (wave & 1) * 64;             // wave M-offset (2x2 wave grid)
    const int wn   = (wave >> 1) * 64;            // wave N-offset
    const int l31  = lane & 31;
    const int q5   = lane >> 5;

    f32x16 acc[2][2];
#pragma unroll
    for (int mi = 0; mi < 2; mi++)
#pragma unroll
        for (int ni = 0; ni < 2; ni++)
#pragma unroll
            for (int e = 0; e < 16; e++) acc[mi][ni][e] = 0.f;

    const int ntaps = (which == 2) ? 1 : 3;
    const u16* Wbase0 = (which == 0) ? Wqt : (which == 1) ? Wkt : Wv;

    for (int tap = 0; tap < ntaps; ++tap) {
        int tsrc = (which == 2) ? t : (t + tap - 2);
        if (tsrc < 0) continue;                   // causal zero-pad (block-uniform)
        const u16* Abase = Xb + ((size_t)(b * 64 + tsrc) * 128) * 512;
        const u16* Wbase = Wbase0 + (which == 2 ? 0 : (size_t)tap * 262144);

        for (int kk = 0; kk < 512; kk += 64) {
            __syncthreads();
            // stage 128x64 A and B tiles: 1024 16B chunks each, 4/thread.
            // LDS dest is linear (chunk p -> bytes [p*16, p*16+16)); global
            // source picks the element whose swizzled home is chunk p:
            //   row = p>>3, srcslot = (p&7) ^ (row&7).
#pragma unroll
            for (int i = 0; i < 4; ++i) {
                int p   = i * 256 + tid;          // 0..1023
                int row = p >> 3;
                int sl  = (p & 7) ^ (row & 7);
                gload_lds16(Abase + (size_t)row * 512 + kk + sl * 8, As + p * 8);
                gload_lds16(Wbase + (size_t)(cb + row) * 512 + kk + sl * 8, Bs + p * 8);
            }
            __syncthreads();

            // A-frag: row = l31 (+tile offs), k0 = k2*16 + q5*8 (8 contiguous)
            // read address XOR-swizzled with (row&7)<<3 (u16 units).
#pragma unroll
            for (int half = 0; half < 2; ++half) {
                bf16x8 af[2][2], bf[2][2];
#pragma unroll
                for (int mi = 0; mi < 2; mi++) {
                    int r = wm + mi * 32 + l31;
#pragma unroll
                    for (int j = 0; j < 2; j++) {
                        int k2 = half * 2 + j;
                        af[mi][j] = ld8(As + ((r * 64 + k2 * 16 + q5 * 8) ^ ((r & 7) << 3)));
                    }
                }
#pragma unroll
                for (int ni = 0; ni < 2; ni++) {
                    int c = wn + ni * 32 + l31;
#pragma unroll
                    for (int j = 0; j < 2; j++) {
                        int k2 = half * 2 + j;
                        bf[ni][j] = ld8(Bs + ((c * 64 + k2 * 16 + q5 * 8) ^ ((c & 7) << 3)));
                    }
                }
#pragma unroll
                for (int j = 0; j < 2; j++)
#pragma unroll
                    for (int mi = 0; mi < 2; mi++)
#pragma unroll
                        for (int ni = 0; ni < 2; ni++)
                            acc[mi][ni] = __builtin_amdgcn_mfma_f32_32x32x16_bf16(
                                af[mi][j], bf[ni][j], acc[mi][ni], 0, 0, 0);
            }
        }
    }

    // Epilogue. 32x32 C/D layout: col = lane&31, row = (reg&3)+8*(reg>>2)+4*q5.
    float biasv[2];
#pragma unroll
    for (int ni = 0; ni < 2; ni++) {
        int c = cb + wn + ni * 32 + l31;
        biasv[ni] = (which == 0) ? biasq[c] : (which == 1) ? biask[c] : bv[c];
    }
    u16* Outp = (which == 0) ? Qa : (which == 1) ? Ka : Va;
#pragma unroll
    for (int mi = 0; mi < 2; mi++) {
#pragma unroll
        for (int ni = 0; ni < 2; ni++) {
            int c = cb + wn + ni * 32 + l31;
            int h = c >> 6, dd = c & 63;
#pragma unroll
            for (int r = 0; r < 16; r++) {
                int n = wm + mi * 32 + (r & 3) + ((r >> 2) << 3) + (q5 << 2);
                float val = acc[mi][ni][r] + biasv[ni];
                size_t idx = ((((size_t)(brel * 128 + n)) * 8 + h) * 64 + t) * 64 + dd;
                Outp[idx] = f2bf(val);
            }
        }
    }
}

// ---------------------------------------------------------------------------
// K2: attention per (brel,n,h). 64x64 tiles, full softmax in regs.
// Writes output over the (dead) Q buffer in the same [brel][n][h][t][d] layout.
// (unchanged from the 675 us verified version)
// ---------------------------------------------------------------------------
__global__ __launch_bounds__(256) void attn_kernel(
    const u16* __restrict__ Qa, const u16* __restrict__ Ka, const u16* __restrict__ Va,
    u16* __restrict__ AO)
{
    __shared__ __align__(16) u16 Qs[64 * 72];
    __shared__ __align__(16) u16 Ks[64 * 72];
    __shared__ __align__(16) u16 Vt[64 * 72];   // transposed: [d][t]
    __shared__ __align__(16) u16 Ps[64 * 72];

    const int h = blockIdx.x, n = blockIdx.y, brel = blockIdx.z;
    const int tid = threadIdx.x, wave = tid >> 6, lane = tid & 63;
    const int l15 = lane & 15, q4 = lane >> 4;
    const size_t base = ((size_t)((brel * 128 + n) * 8 + h)) * 4096;

#pragma unroll
    for (int i = 0; i < 2; i++) {
        int chunk = i * 256 + tid;                // 0..511
        int row = chunk >> 3, kc = chunk & 7;
        u16x8 vq = *(const u16x8*)(Qa + base + chunk * 8);
        u16x8 vk = *(const u16x8*)(Ka + base + chunk * 8);
        u16x8 vv = *(const u16x8*)(Va + base + chunk * 8);
        *(u16x8*)(Qs + row * 72 + kc * 8) = vq;
        *(u16x8*)(Ks + row * 72 + kc * 8) = vk;
#pragma unroll
        for (int j = 0; j < 8; j++) Vt[(kc * 8 + j) * 72 + row] = vv[j];
    }
    __syncthreads();

    // S = Q K^T  (scale already folded into Q)
    f32x4 s[4];
#pragma unroll
    for (int ni = 0; ni < 4; ni++) s[ni] = f32x4{0.f, 0.f, 0.f, 0.f};
    bf16x8 aq[2];
#pragma unroll
    for (int ks = 0; ks < 2; ks++)
        aq[ks] = ld8(Qs + (wave * 16 + l15) * 72 + ks * 32 + q4 * 8);
#pragma unroll
    for (int ni = 0; ni < 4; ni++) {
        int p = ni * 16 + l15;
#pragma unroll
        for (int ks = 0; ks < 2; ks++) {
            bf16x8 bk8 = ld8(Ks + p * 72 + ks * 32 + q4 * 8);
            s[ni] = __builtin_amdgcn_mfma_f32_16x16x32_bf16(aq[ks], bk8, s[ni], 0, 0, 0);
        }
    }

    // row softmax: rows t = wave*16 + q4*4 + r, entries spread over 16 lanes x 4 frags
    float rmax[4], rsum[4], inv[4];
#pragma unroll
    for (int r = 0; r < 4; r++)
        rmax[r] = fmaxf(fmaxf(s[0][r], s[1][r]), fmaxf(s[2][r], s[3][r]));
#pragma unroll
    for (int m = 1; m < 16; m <<= 1)
#pragma unroll
        for (int r = 0; r < 4; r++)
            rmax[r] = fmaxf(rmax[r], __shfl_xor(rmax[r], m, 64));
    float e[4][4];
#pragma unroll
    for (int r = 0; r < 4; r++) rsum[r] = 0.f;
#pragma unroll
    for (int ni = 0; ni < 4; ni++)
#pragma unroll
        for (int r = 0; r < 4; r++) {
            e[ni][r] = __expf(s[ni][r] - rmax[r]);
            rsum[r] += e[ni][r];
        }
#pragma unroll
    for (int m = 1; m < 16; m <<= 1)
#pragma unroll
        for (int r = 0; r < 4; r++)
            rsum[r] += __shfl_xor(rsum[r], m, 64);
#pragma unroll
    for (int r = 0; r < 4; r++) inv[r] = 1.0f / rsum[r];

    // store unnormalized P (bf16) in A-layout source
#pragma unroll
    for (int ni = 0; ni < 4; ni++)
#pragma unroll
        for (int r = 0; r < 4; r++)
            Ps[(wave * 16 + q4 * 4 + r) * 72 + ni * 16 + l15] = f2bf(e[ni][r]);
    __syncthreads();

    // O = P V   (A = P rows t, B = V^T rows d)
    f32x4 o[4];
#pragma unroll
    for (int ni = 0; ni < 4; ni++) o[ni] = f32x4{0.f, 0.f, 0.f, 0.f};
    bf16x8 ap[2];
#pragma unroll
    for (int ks = 0; ks < 2; ks++)
        ap[ks] = ld8(Ps + (wave * 16 + l15) * 72 + ks * 32 + q4 * 8);
#pragma unroll
    for (int ni = 0; ni < 4; ni++) {
        int dd = ni * 16 + l15;
#pragma unroll
        for (int ks = 0; ks < 2; ks++) {
            bf16x8 bv8 = ld8(Vt + dd * 72 + ks * 32 + q4 * 8);
            o[ni] = __builtin_amdgcn_mfma_f32_16x16x32_bf16(ap[ks], bv8, o[ni], 0, 0, 0);
        }
    }

#pragma unroll
    for (int ni = 0; ni < 4; ni++) {
        int dd = ni * 16 + l15;
#pragma unroll
        for (int r = 0; r < 4; r++) {
            int tt = wave * 16 + q4 * 4 + r;
            AO[base + tt * 64 + dd] = f2bf(o[ni][r] * inv[r]);
        }
    }
}

// ---------------------------------------------------------------------------
// K3: output projection. A rows from AO in [brel][n][h][t][d] layout (bf16),
// B = Wo (bf16). Writes f32 [B,T,N,D] at absolute b.
// Same BK=64 / 32x32x16 / XOR-swizzle structure as qkv_gemm.
// ---------------------------------------------------------------------------
__global__ __launch_bounds__(256) void proj_gemm(
    const u16* __restrict__ AO, const u16* __restrict__ Wo, const float* __restrict__ bo,
    float* __restrict__ Out, int b0)
{
    __shared__ __align__(16) u16 As[128 * 64];
    __shared__ __align__(16) u16 Bs[128 * 64];

    const int cb   = blockIdx.x * 128;
    const int rt   = blockIdx.y;
    const int brel = rt >> 6;
    const int b    = b0 + brel;
    const int t    = rt & 63;

    const int tid  = threadIdx.x;
    const int wave = tid >> 6;
    const int lane = tid & 63;
    const int wm   = (wave & 1) * 64;
    const int wn   = (wave >> 1) * 64;
    const int l31  = lane & 31;
    const int q5   = lane >> 5;

    f32x16 acc[2][2];
#pragma unroll
    for (int mi = 0; mi < 2; mi++)
#pragma unroll
        for (int ni = 0; ni < 2; ni++)
#pragma unroll
            for (int e = 0; e < 16; e++) acc[mi][ni][e] = 0.f;

    for (int kk = 0; kk < 512; kk += 64) {
        __syncthreads();
#pragma unroll
        for (int i = 0; i < 4; ++i) {
            int p   = i * 256 + tid;
            int row = p >> 3;
            int sl  = (p & 7) ^ (row & 7);
            int k   = kk + sl * 8;
            int hh  = k >> 6, d0 = k & 63;
            const u16* ga = AO + ((((size_t)(brel * 128 + row)) * 8 + hh) * 64 + t) * 64 + d0;
            gload_lds16(ga, As + p * 8);
            gload_lds16(Wo + (size_t)(cb + row) * 512 + k, Bs + p * 8);
        }
        __syncthreads();

#pragma unroll
        for (int half = 0; half < 2; ++half) {
            bf16x8 af[2][2], bf[2][2];
#pragma unroll
            for (int mi = 0; mi < 2; mi++) {
                int r = wm + mi * 32 + l31;
#pragma unroll
                for (int j = 0; j < 2; j++) {
                    int k2 = half * 2 + j;
                    af[mi][j] = ld8(As + ((r * 64 + k2 * 16 + q5 * 8) ^ ((r & 7) << 3)));
                }
            }
#pragma unroll
            for (int ni = 0; ni < 2; ni++) {
                int c = wn + ni * 32 + l31;
#pragma unroll
                for (int j = 0; j < 2; j++) {
                    int k2 = half * 2 + j;
                    bf[ni][j] = ld8(Bs + ((c * 64 + k2 * 16 + q5 * 8) ^ ((c & 7) << 3)));
                }
            }
#pragma unroll
            for (int j = 0; j < 2; j++)
#pragma unroll
                for (int mi = 0; mi < 2; mi++)
#pragma unroll
                    for (int ni = 0; ni < 2; ni++)
                        acc[mi][ni] = __builtin_amdgcn_mfma_f32_32x32x16_bf16(
                            af[mi][j], bf[ni][j], acc[mi][ni], 0, 0, 0);
        }
    }

#pragma unroll
    for (int mi = 0; mi < 2; mi++) {
#pragma unroll
        for (int ni = 0; ni < 2; ni++) {
            int c = cb + wn + ni * 32 + l31;
            float bias = bo[c];
#pragma unroll
            for (int r = 0; r < 16; r++) {
                int n = wm + mi * 32 + (r & 3) + ((r >> 2) << 3) + (q5 << 2);
                float val = acc[mi][ni][r] + bias;
                size_t idx = (((size_t)(b * 64 + t)) * 128 + n) * 512 + c;
                Out[idx] = val;
            }
        }
    }
}

// ---------------------------------------------------------------------------
extern "C" void kernel_launch(void* const* d_in, const int* in_sizes, int n_in,
                              void* d_out, int out_size, void* d_ws, size_t ws_size,
                              hipStream_t stream)
{
    const float* X     = (const float*)d_in[0];
    const float* Wq    = (const float*)d_in[1];
    const float* bq    = (const float*)d_in[2];
    const float* gq    = (const float*)d_in[3];
    const float* betaq = (const float*)d_in[4];
    const float* mq    = (const float*)d_in[5];
    const float* vq    = (const float*)d_in[6];
    const float* Wk    = (const float*)d_in[7];
    const float* bk    = (const float*)d_in[8];
    const float* gk    = (const float*)d_in[9];
    const float* betak = (const float*)d_in[10];
    const float* mk    = (const float*)d_in[11];
    const float* vk    = (const float*)d_in[12];
    const float* Wv    = (const float*)d_in[13];
    const float* bv    = (const float*)d_in[14];
    const float* Wo    = (const float*)d_in[15];
    const float* bo    = (const float*)d_in[16];
    float* outp = (float*)d_out;
    u16*   ws   = (u16*)d_ws;

    // X/out total = 8*64*128*512 = 33,554,432 elements.
    const size_t XTOT   = 33554432;
    const size_t XSLICE = 4194304;    // per-batch elems (64*128*512)

    // big path ws need: 3*XTOT + weights ~ 197 MiB
    const bool big = ws_size >= (size_t)206000000;

    u16 *Xb, *Qa, *Ka, *Wqt;
    if (big) {
        Xb  = ws;                     // 33.5M u16
        Qa  = ws + XTOT;              // 33.5M
        Ka  = Qa + XTOT;              // 33.5M
        Wqt = Ka + XTOT;
    } else {
        Xb  = ws;                     // 4.19M (one batch)
        Qa  = ws + XSLICE;
        Ka  = Qa + XSLICE;
        Wqt = Ka + XSLICE;
    }
    u16* Wkt = Wqt + 786432;
    u16* Wvb = Wkt + 786432;
    u16* Wob = Wvb + 262144;
    float* biasq = (float*)(Wob + 262144);
    float* biask = biasq + 512;

    hipLaunchKernelGGL(prep_weights, dim3(6144), dim3(256), 0, stream,
                       Wq, gq, vq, Wk, gk, vk, Wqt, Wkt);
    hipLaunchKernelGGL(prep_bias, dim3(2), dim3(256), 0, stream,
                       bq, gq, betaq, mq, vq, bk, gk, betak, mk, vk, biasq, biask);
    hipLaunchKernelGGL(f32_to_bf16, dim3(256), dim3(256), 0, stream, Wv, Wvb, 262144);
    hipLaunchKernelGGL(f32_to_bf16, dim3(256), dim3(256), 0, stream, Wo, Wob, 262144);

    if (big) {
        // V staged as bf16 in the first half of d_out (dead before proj writes)
        u16* Va = (u16*)d_out;
        hipLaunchKernelGGL(f32_to_bf16, dim3(32768), dim3(256), 0, stream,
                           X, Xb, (int)XTOT);
        hipLaunchKernelGGL(qkv_gemm, dim3(12, 512), dim3(256), 0, stream,
                           Xb, Wqt, Wkt, Wvb, biasq, biask, bv, Qa, Ka, Va, 0);
        hipLaunchKernelGGL(attn_kernel, dim3(8, 128, 8), dim3(256), 0, stream,
                           Qa, Ka, Va, Qa);
        hipLaunchKernelGGL(proj_gemm, dim3(4, 512), dim3(256), 0, stream,
                           Qa, Wob, bo, outp, 0);
    } else {
        for (int p = 0; p < 8; ++p) {
            // V bf16 staged at the start of batch p's own f32 output region
            // (16.7 MB region, V slice = 8.4 MB; dead before proj writes it).
            u16* Va = (u16*)d_out + (size_t)p * 2 * XSLICE;
            hipLaunchKernelGGL(f32_to_bf16, dim3(4096), dim3(256), 0, stream,
                               X + (size_t)p * XSLICE, Xb, (int)XSLICE);
            // Xb holds only batch p at offset 0; kernel indexes X by absolute
            // b, so pre-offset the pointer.
            hipLaunchKernelGGL(qkv_gemm, dim3(12, 64), dim3(256), 0, stream,
                               Xb - (size_t)p * XSLICE, Wqt, Wkt, Wvb,
                               biasq, biask, bv, Qa, Ka, Va, p);
            hipLaunchKernelGGL(attn_kernel, dim3(8, 128, 1), dim3(256), 0, stream,
                               Qa, Ka, Va, Qa);
            hipLaunchKernelGGL(proj_gemm, dim3(4, 64), dim3(256), 0, stream,
                               Qa, Wob, bo, outp, p);
        }
    }
}

// Round 2
// 614.323 us; speedup vs baseline: 1.0321x; 1.0321x over previous
//
#include <hip/hip_runtime.h>

typedef unsigned short u16;
typedef u16    u16x4  __attribute__((ext_vector_type(4)));
typedef u16    u16x8  __attribute__((ext_vector_type(8)));
typedef __bf16 bf16x8 __attribute__((ext_vector_type(8)));
typedef float  f32x4  __attribute__((ext_vector_type(4)));

#define DEV static __device__ __forceinline__

DEV float bf2f(u16 h) {
    union { unsigned int u; float f; } c; c.u = ((unsigned int)h) << 16; return c.f;
}
DEV u16 f2bf(float f) {
    union { float f; unsigned int u; } c; c.f = f;
    unsigned int u = c.u + 0x7FFFu + ((c.u >> 16) & 1u);
    return (u16)(u >> 16);
}
DEV bf16x8 ld8(const u16* p) {
    return __builtin_bit_cast(bf16x8, *(const u16x8*)p);
}
DEV void gload_lds16(const u16* g, u16* l) {
    __builtin_amdgcn_global_load_lds((__attribute__((address_space(1))) void*)g,
                                     (__attribute__((address_space(3))) void*)l,
                                     16, 0, 0);
}
// raw barrier with compiler memory fences (no vmcnt drain, unlike __syncthreads)
DEV void bar() {
    asm volatile("" ::: "memory");
    __builtin_amdgcn_s_barrier();
    asm volatile("" ::: "memory");
}
#define VMCNT(n) asm volatile("s_waitcnt vmcnt(" #n ")" ::: "memory")

// ---------------------------------------------------------------------------
// f32 -> bf16 elementwise convert (n multiple of 4).
// ---------------------------------------------------------------------------
__global__ __launch_bounds__(256) void f32_to_bf16(
    const float* __restrict__ src, u16* __restrict__ dst, int n)
{
    int i = (blockIdx.x * 256 + threadIdx.x) * 4;
    if (i < n) {
        f32x4 v = *(const f32x4*)(src + i);
        u16x4 o;
        o[0] = f2bf(v[0]); o[1] = f2bf(v[1]); o[2] = f2bf(v[2]); o[3] = f2bf(v[3]);
        *(u16x4*)(dst + i) = o;
    }
}

// ---------------------------------------------------------------------------
// Prep: conv weights [O][I][KS] -> [O][tap][I]  (row o has K=1536 contiguous:
// tap-major within row), fold BN scale (0.125 attn scale into Q). bf16 out.
// ---------------------------------------------------------------------------
__global__ __launch_bounds__(256) void prep_weights(
    const float* __restrict__ Wq, const float* __restrict__ gq, const float* __restrict__ vq,
    const float* __restrict__ Wk, const float* __restrict__ gk, const float* __restrict__ vk,
    u16* __restrict__ Wqt, u16* __restrict__ Wkt)
{
    int idx = blockIdx.x * 256 + threadIdx.x;        // 0 .. 2*786432-1
    int mat = idx >= 786432;                         // 0=q, 1=k
    int rem = idx - mat * 786432;
    int tap = rem / 262144;
    int oi  = rem - tap * 262144;
    int o = oi >> 9, i = oi & 511;
    const float* W = mat ? Wk : Wq;
    const float* g = mat ? gk : gq;
    const float* v = mat ? vk : vq;
    float s = g[o] * rsqrtf(v[o] + 1e-5f) * (mat ? 1.0f : 0.125f);
    float w = W[(o * 512 + i) * 3 + tap] * s;
    (mat ? Wkt : Wqt)[(o * 3 + tap) * 512 + i] = f2bf(w);   // [o][1536]
}

__global__ __launch_bounds__(256) void prep_bias(
    const float* bq, const float* gq, const float* betaq, const float* mq, const float* vq,
    const float* bk, const float* gk, const float* betak, const float* mk, const float* vk,
    float* __restrict__ biasq, float* __restrict__ biask, u16* __restrict__ zb)
{
    int o = blockIdx.x * 256 + threadIdx.x;
    if (o < 512) {
        float sq = gq[o] * rsqrtf(vq[o] + 1e-5f);
        biasq[o] = ((bq[o] - mq[o]) * sq + betaq[o]) * 0.125f;
        float sk = gk[o] * rsqrtf(vk[o] + 1e-5f);
        biask[o] = (bk[o] - mk[o]) * sk + betak[o];
    }
    if (blockIdx.x == 0 && threadIdx.x < 64) zb[threadIdx.x] = 0;  // zero-pad source
}

// ---------------------------------------------------------------------------
// K1: fused QKV, 8-phase counted-vmcnt schedule (T2+T3+T4+T5, + T1 grid swz).
// One block: 256 output rows (= 2 t's x 128 n) x 256 output channels.
// 512 threads, 8 waves, wave tile 256x32. BK=64, 2x double-buffered LDS.
//
// K-tiles: Q/K kt in [0,24) (K=1536, tap = kt>>3, weights laid [o][1536]);
//          V   kt in [0,8).
// Per K-tile: 4 phases (row-quadrants q of the 256-row A tile).
//   phase: {ds_read frags; stage one half-tile of kt+1; bar; MFMA x16; bar}
// Stage order for kt+1 during kt: ph0:B0 ph1:B1 ph2:A0 ph3:A1.
// Waits: VMCNT(2) at tile boundary (B0,B1,A0 of next landed, A1 in flight),
//        VMCNT(4) after ph1 (A1 of current landed before ph2 reads rows 128+).
// Counted vmcnt sits BEFORE a barrier: each wave drains its own contribution,
// the barrier composes this into an all-waves guarantee.
//
// LDS T2 swizzle: 16B slot sl of row r holds global slot sl^(r&7); stage
// pre-swizzles the GLOBAL source (gload_lds dest must stay linear), frag
// reads XOR the same mask. Causal t<0: block-uniform redirect to a zero page.
// ---------------------------------------------------------------------------
__global__ __launch_bounds__(512, 1) void qkv8(
    const u16* __restrict__ Xb,
    const u16* __restrict__ Wq3, const u16* __restrict__ Wk3, const u16* __restrict__ Wv1,
    const float* __restrict__ biasq, const float* __restrict__ biask, const float* __restrict__ bv,
    const u16* __restrict__ zbuf,
    u16* __restrict__ Qa, u16* __restrict__ Ka, u16* __restrict__ Va, int b0)
{
    __shared__ __align__(16) u16 As[2 * 16384];   // [buf][256][64]
    __shared__ __align__(16) u16 Bs[2 * 16384];

    // T1: XCD-chunked bijective swizzle (total is 1536 or 192, both %8==0).
    const int total = gridDim.x;
    const int cpx   = total >> 3;
    const int s     = blockIdx.x;
    const int w     = (s & 7) * cpx + (s >> 3);
    const int wc    = w % 6;                  // which*2 + cb-index (fastest)
    const int bt    = w / 6;                  // (brel, tpair)
    const int which = wc >> 1;                // 0=q 1=k 2=v
    const int cb    = (wc & 1) * 256;
    const int tpair = bt & 31;
    const int brel  = bt >> 5;
    const int b     = b0 + brel;

    const int tid  = threadIdx.x;
    const int wave = tid >> 6;
    const int lane = tid & 63;
    const int l15  = lane & 15;
    const int q4   = lane >> 4;
    const int wn   = wave;                    // wave covers cols [wn*32, wn*32+32)

    const u16* WB = (which == 0) ? Wq3 : (which == 1) ? Wk3 : Wv1;
    const int  KW = (which == 2) ? 512 : 1536;
    const int  NT = (which == 2) ? 8 : 24;

    f32x4 acc[16][2];
#pragma unroll
    for (int a = 0; a < 16; ++a)
#pragma unroll
        for (int ni = 0; ni < 2; ++ni) acc[a][ni] = f32x4{0.f, 0.f, 0.f, 0.f};

    auto stageA = [&](int kt, int bufp, int h) {
        int tap  = (which == 2) ? 0 : (kt >> 3);
        int kb   = (which == 2) ? (kt << 6) : ((kt & 7) << 6);
        int tsrc = 2 * tpair + h + ((which == 2) ? 0 : (tap - 2));
#pragma unroll
        for (int j = 0; j < 2; ++j) {
            int slot = h * 1024 + j * 512 + tid;
            int r = slot >> 3, sl = slot & 7;
            const u16* src = (tsrc < 0) ? zbuf
                : Xb + ((size_t)((b * 64 + tsrc) * 128 + (r & 127))) * 512 + kb
                     + ((sl ^ (r & 7)) << 3);
            gload_lds16(src, As + bufp * 16384 + slot * 8);
        }
    };
    auto stageB = [&](int kt, int bufp, int h) {
#pragma unroll
        for (int j = 0; j < 2; ++j) {
            int slot = h * 1024 + j * 512 + tid;
            int r = slot >> 3, sl = slot & 7;
            const u16* src = WB + (size_t)(cb + r) * KW + (kt << 6)
                           + ((sl ^ (r & 7)) << 3);
            gload_lds16(src, Bs + bufp * 16384 + slot * 8);
        }
    };

#define PHASE_READ_B() \
    _Pragma("unroll") \
    for (int ni = 0; ni < 2; ++ni) { \
        _Pragma("unroll") \
        for (int ks = 0; ks < 2; ++ks) { \
            int rr = wn * 32 + ni * 16 + l15; \
            bfr[ni][ks] = ld8(Bcur + ((rr * 64 + ks * 32 + q4 * 8) ^ ((l15 & 7) << 3))); \
        } \
    }

#define PHASE_READ_A(q) \
    _Pragma("unroll") \
    for (int mi = 0; mi < 4; ++mi) { \
        _Pragma("unroll") \
        for (int ks = 0; ks < 2; ++ks) { \
            int rr = (q) * 64 + mi * 16 + l15; \
            af[mi][ks] = ld8(Acur + ((rr * 64 + ks * 32 + q4 * 8) ^ ((l15 & 7) << 3))); \
        } \
    }

#define PHASE_MFMA(q) \
    __builtin_amdgcn_s_setprio(1); \
    _Pragma("unroll") \
    for (int ks = 0; ks < 2; ++ks) \
        _Pragma("unroll") \
        for (int mi = 0; mi < 4; ++mi) \
            _Pragma("unroll") \
            for (int ni = 0; ni < 2; ++ni) \
                acc[(q) * 4 + mi][ni] = __builtin_amdgcn_mfma_f32_16x16x32_bf16( \
                    af[mi][ks], bfr[ni][ks], acc[(q) * 4 + mi][ni], 0, 0, 0); \
    __builtin_amdgcn_s_setprio(0);

    // prologue: stage kt=0 (B0,B1,A0,A1); allow A1 to stay in flight
    stageB(0, 0, 0); stageB(0, 0, 1);
    stageA(0, 0, 0); stageA(0, 0, 1);
    VMCNT(2);
    bar();

    for (int kt = 0; kt < NT; ++kt) {
        const int cur = kt & 1, nxt = cur ^ 1;
        const bool pf = (kt + 1 < NT);
        const u16* Acur = As + cur * 16384;
        const u16* Bcur = Bs + cur * 16384;
        bf16x8 af[4][2], bfr[2][2];

        // ph0: rows 0-63 (+ B frags for whole K-tile)
        PHASE_READ_B();
        PHASE_READ_A(0);
        if (pf) stageB(kt + 1, nxt, 0);
        bar();
        PHASE_MFMA(0);
        bar();

        // ph1: rows 64-127
        PHASE_READ_A(1);
        if (pf) stageB(kt + 1, nxt, 1);
        bar();
        PHASE_MFMA(1);
        VMCNT(4);                 // current kt's A1 (rows 128-255) landed
        bar();

        // ph2: rows 128-191
        PHASE_READ_A(2);
        if (pf) stageA(kt + 1, nxt, 0);
        bar();
        PHASE_MFMA(2);
        bar();

        // ph3: rows 192-255
        PHASE_READ_A(3);
        if (pf) stageA(kt + 1, nxt, 1);
        bar();
        PHASE_MFMA(3);
        VMCNT(2);                 // next kt's B0,B1,A0 landed; A1 in flight
        bar();
    }

#undef PHASE_READ_B
#undef PHASE_READ_A
#undef PHASE_MFMA

    // Epilogue: 16x16x32 C/D layout: col=lane&15, row=q4*4+reg within frag.
    const float* biasp = (which == 0) ? biasq : (which == 1) ? biask : bv;
    float bias2[2];
#pragma unroll
    for (int ni = 0; ni < 2; ++ni) bias2[ni] = biasp[cb + wn * 32 + ni * 16 + l15];
    u16* Outp = (which == 0) ? Qa : (which == 1) ? Ka : Va;
#pragma unroll
    for (int a = 0; a < 16; ++a) {
#pragma unroll
        for (int ni = 0; ni < 2; ++ni) {
            int c = cb + wn * 32 + ni * 16 + l15;
            int h = c >> 6, dd = c & 63;
#pragma unroll
            for (int r = 0; r < 4; ++r) {
                int row = a * 16 + q4 * 4 + r;       // 0..255
                int n = row & 127, tt = 2 * tpair + (row >> 7);
                float val = acc[a][ni][r] + bias2[ni];
                Outp[((((size_t)(brel * 128 + n)) * 8 + h) * 64 + tt) * 64 + dd] = f2bf(val);
            }
        }
    }
}

// ---------------------------------------------------------------------------
// K2: attention per (brel,n,h). 64x64 tiles, full softmax in regs.
// Writes output over the (dead) Q buffer in the same [brel][n][h][t][d] layout.
// (unchanged; verified)
// ---------------------------------------------------------------------------
__global__ __launch_bounds__(256) void attn_kernel(
    const u16* __restrict__ Qa, const u16* __restrict__ Ka, const u16* __restrict__ Va,
    u16* __restrict__ AO)
{
    __shared__ __align__(16) u16 Qs[64 * 72];
    __shared__ __align__(16) u16 Ks[64 * 72];
    __shared__ __align__(16) u16 Vt[64 * 72];   // transposed: [d][t]
    __shared__ __align__(16) u16 Ps[64 * 72];

    const int h = blockIdx.x, n = blockIdx.y, brel = blockIdx.z;
    const int tid = threadIdx.x, wave = tid >> 6, lane = tid & 63;
    const int l15 = lane & 15, q4 = lane >> 4;
    const size_t base = ((size_t)((brel * 128 + n) * 8 + h)) * 4096;

#pragma unroll
    for (int i = 0; i < 2; i++) {
        int chunk = i * 256 + tid;                // 0..511
        int row = chunk >> 3, kc = chunk & 7;
        u16x8 vq = *(const u16x8*)(Qa + base + chunk * 8);
        u16x8 vk = *(const u16x8*)(Ka + base + chunk * 8);
        u16x8 vv = *(const u16x8*)(Va + base + chunk * 8);
        *(u16x8*)(Qs + row * 72 + kc * 8) = vq;
        *(u16x8*)(Ks + row * 72 + kc * 8) = vk;
#pragma unroll
        for (int j = 0; j < 8; j++) Vt[(kc * 8 + j) * 72 + row] = vv[j];
    }
    __syncthreads();

    // S = Q K^T  (scale already folded into Q)
    f32x4 s[4];
#pragma unroll
    for (int ni = 0; ni < 4; ni++) s[ni] = f32x4{0.f, 0.f, 0.f, 0.f};
    bf16x8 aq[2];
#pragma unroll
    for (int ks = 0; ks < 2; ks++)
        aq[ks] = ld8(Qs + (wave * 16 + l15) * 72 + ks * 32 + q4 * 8);
#pragma unroll
    for (int ni = 0; ni < 4; ni++) {
        int p = ni * 16 + l15;
#pragma unroll
        for (int ks = 0; ks < 2; ks++) {
            bf16x8 bk8 = ld8(Ks + p * 72 + ks * 32 + q4 * 8);
            s[ni] = __builtin_amdgcn_mfma_f32_16x16x32_bf16(aq[ks], bk8, s[ni], 0, 0, 0);
        }
    }

    // row softmax
    float rmax[4], rsum[4], inv[4];
#pragma unroll
    for (int r = 0; r < 4; r++)
        rmax[r] = fmaxf(fmaxf(s[0][r], s[1][r]), fmaxf(s[2][r], s[3][r]));
#pragma unroll
    for (int m = 1; m < 16; m <<= 1)
#pragma unroll
        for (int r = 0; r < 4; r++)
            rmax[r] = fmaxf(rmax[r], __shfl_xor(rmax[r], m, 64));
    float e[4][4];
#pragma unroll
    for (int r = 0; r < 4; r++) rsum[r] = 0.f;
#pragma unroll
    for (int ni = 0; ni < 4; ni++)
#pragma unroll
        for (int r = 0; r < 4; r++) {
            e[ni][r] = __expf(s[ni][r] - rmax[r]);
            rsum[r] += e[ni][r];
        }
#pragma unroll
    for (int m = 1; m < 16; m <<= 1)
#pragma unroll
        for (int r = 0; r < 4; r++)
            rsum[r] += __shfl_xor(rsum[r], m, 64);
#pragma unroll
    for (int r = 0; r < 4; r++) inv[r] = 1.0f / rsum[r];

    // store unnormalized P (bf16)
#pragma unroll
    for (int ni = 0; ni < 4; ni++)
#pragma unroll
        for (int r = 0; r < 4; r++)
            Ps[(wave * 16 + q4 * 4 + r) * 72 + ni * 16 + l15] = f2bf(e[ni][r]);
    __syncthreads();

    // O = P V
    f32x4 o[4];
#pragma unroll
    for (int ni = 0; ni < 4; ni++) o[ni] = f32x4{0.f, 0.f, 0.f, 0.f};
    bf16x8 ap[2];
#pragma unroll
    for (int ks = 0; ks < 2; ks++)
        ap[ks] = ld8(Ps + (wave * 16 + l15) * 72 + ks * 32 + q4 * 8);
#pragma unroll
    for (int ni = 0; ni < 4; ni++) {
        int dd = ni * 16 + l15;
#pragma unroll
        for (int ks = 0; ks < 2; ks++) {
            bf16x8 bv8 = ld8(Vt + dd * 72 + ks * 32 + q4 * 8);
            o[ni] = __builtin_amdgcn_mfma_f32_16x16x32_bf16(ap[ks], bv8, o[ni], 0, 0, 0);
        }
    }

#pragma unroll
    for (int ni = 0; ni < 4; ni++) {
        int dd = ni * 16 + l15;
#pragma unroll
        for (int r = 0; r < 4; r++) {
            int tt = wave * 16 + q4 * 4 + r;
            AO[base + tt * 64 + dd] = f2bf(o[ni][r] * inv[r]);
        }
    }
}

// ---------------------------------------------------------------------------
// K3: output projection (2-barrier BK=64 structure with T2 swizzle; ~10% of
// runtime — untouched this round).
// ---------------------------------------------------------------------------
__global__ __launch_bounds__(256) void proj_gemm(
    const u16* __restrict__ AO, const u16* __restrict__ Wo, const float* __restrict__ bo,
    float* __restrict__ Out, int b0)
{
    __shared__ __align__(16) u16 As[128 * 64];
    __shared__ __align__(16) u16 Bs[128 * 64];

    const int cb   = blockIdx.x * 128;
    const int rt   = blockIdx.y;
    const int brel = rt >> 6;
    const int b    = b0 + brel;
    const int t    = rt & 63;

    const int tid  = threadIdx.x;
    const int wave = tid >> 6;
    const int lane = tid & 63;
    const int wm   = (wave & 1) * 64;
    const int wn   = (wave >> 1) * 64;
    const int l31  = lane & 31;
    const int q5   = lane >> 5;

    typedef float f32x16_t __attribute__((ext_vector_type(16)));
    f32x16_t acc[2][2];
#pragma unroll
    for (int mi = 0; mi < 2; mi++)
#pragma unroll
        for (int ni = 0; ni < 2; ni++)
#pragma unroll
            for (int e = 0; e < 16; e++) acc[mi][ni][e] = 0.f;

    for (int kk = 0; kk < 512; kk += 64) {
        __syncthreads();
#pragma unroll
        for (int i = 0; i < 4; ++i) {
            int p   = i * 256 + tid;
            int row = p >> 3;
            int sl  = (p & 7) ^ (row & 7);
            int k   = kk + sl * 8;
            int hh  = k >> 6, d0 = k & 63;
            const u16* ga = AO + ((((size_t)(brel * 128 + row)) * 8 + hh) * 64 + t) * 64 + d0;
            gload_lds16(ga, As + p * 8);
            gload_lds16(Wo + (size_t)(cb + row) * 512 + k, Bs + p * 8);
        }
        __syncthreads();

#pragma unroll
        for (int half = 0; half < 2; ++half) {
            bf16x8 af[2][2], bf[2][2];
#pragma unroll
            for (int mi = 0; mi < 2; mi++) {
                int r = wm + mi * 32 + l31;
#pragma unroll
                for (int j = 0; j < 2; j++) {
                    int k2 = half * 2 + j;
                    af[mi][j] = ld8(As + ((r * 64 + k2 * 16 + q5 * 8) ^ ((r & 7) << 3)));
                }
            }
#pragma unroll
            for (int ni = 0; ni < 2; ni++) {
                int c = wn + ni * 32 + l31;
#pragma unroll
                for (int j = 0; j < 2; j++) {
                    int k2 = half * 2 + j;
                    bf[ni][j] = ld8(Bs + ((c * 64 + k2 * 16 + q5 * 8) ^ ((c & 7) << 3)));
                }
            }
#pragma unroll
            for (int j = 0; j < 2; j++)
#pragma unroll
                for (int mi = 0; mi < 2; mi++)
#pragma unroll
                    for (int ni = 0; ni < 2; ni++)
                        acc[mi][ni] = __builtin_amdgcn_mfma_f32_32x32x16_bf16(
                            af[mi][j], bf[ni][j], acc[mi][ni], 0, 0, 0);
        }
    }

#pragma unroll
    for (int mi = 0; mi < 2; mi++) {
#pragma unroll
        for (int ni = 0; ni < 2; ni++) {
            int c = cb + wn + ni * 32 + l31;
            float bias = bo[c];
#pragma unroll
            for (int r = 0; r < 16; r++) {
                int n = wm + mi * 32 + (r & 3) + ((r >> 2) << 3) + (q5 << 2);
                float val = acc[mi][ni][r] + bias;
                size_t idx = (((size_t)(b * 64 + t)) * 128 + n) * 512 + c;
                Out[idx] = val;
            }
        }
    }
}

// ---------------------------------------------------------------------------
extern "C" void kernel_launch(void* const* d_in, const int* in_sizes, int n_in,
                              void* d_out, int out_size, void* d_ws, size_t ws_size,
                              hipStream_t stream)
{
    const float* X     = (const float*)d_in[0];
    const float* Wq    = (const float*)d_in[1];
    const float* bq    = (const float*)d_in[2];
    const float* gq    = (const float*)d_in[3];
    const float* betaq = (const float*)d_in[4];
    const float* mq    = (const float*)d_in[5];
    const float* vq    = (const float*)d_in[6];
    const float* Wk    = (const float*)d_in[7];
    const float* bk    = (const float*)d_in[8];
    const float* gk    = (const float*)d_in[9];
    const float* betak = (const float*)d_in[10];
    const float* mk    = (const float*)d_in[11];
    const float* vk    = (const float*)d_in[12];
    const float* Wv    = (const float*)d_in[13];
    const float* bv    = (const float*)d_in[14];
    const float* Wo    = (const float*)d_in[15];
    const float* bo    = (const float*)d_in[16];
    float* outp = (float*)d_out;
    u16*   ws   = (u16*)d_ws;

    const size_t XTOT   = 33554432;   // 8*64*128*512
    const size_t XSLICE = 4194304;    // per-batch elems

    const bool big = ws_size >= (size_t)206000000;

    u16 *Xb, *Qa, *Ka, *Wqt;
    if (big) {
        Xb  = ws;
        Qa  = ws + XTOT;
        Ka  = Qa + XTOT;
        Wqt = Ka + XTOT;
    } else {
        Xb  = ws;
        Qa  = ws + XSLICE;
        Ka  = Qa + XSLICE;
        Wqt = Ka + XSLICE;
    }
    u16* Wkt = Wqt + 786432;
    u16* Wvb = Wkt + 786432;
    u16* Wob = Wvb + 262144;
    float* biasq = (float*)(Wob + 262144);
    float* biask = biasq + 512;
    u16*   zbuf  = (u16*)(biask + 512);   // 64 u16 zero page

    hipLaunchKernelGGL(prep_weights, dim3(6144), dim3(256), 0, stream,
                       Wq, gq, vq, Wk, gk, vk, Wqt, Wkt);
    hipLaunchKernelGGL(prep_bias, dim3(2), dim3(256), 0, stream,
                       bq, gq, betaq, mq, vq, bk, gk, betak, mk, vk, biasq, biask, zbuf);
    hipLaunchKernelGGL(f32_to_bf16, dim3(256), dim3(256), 0, stream, Wv, Wvb, 262144);
    hipLaunchKernelGGL(f32_to_bf16, dim3(256), dim3(256), 0, stream, Wo, Wob, 262144);

    if (big) {
        u16* Va = (u16*)d_out;
        hipLaunchKernelGGL(f32_to_bf16, dim3(32768), dim3(256), 0, stream,
                           X, Xb, (int)XTOT);
        hipLaunchKernelGGL(qkv8, dim3(1536), dim3(512), 0, stream,
                           Xb, Wqt, Wkt, Wvb, biasq, biask, bv, zbuf, Qa, Ka, Va, 0);
        hipLaunchKernelGGL(attn_kernel, dim3(8, 128, 8), dim3(256), 0, stream,
                           Qa, Ka, Va, Qa);
        hipLaunchKernelGGL(proj_gemm, dim3(4, 512), dim3(256), 0, stream,
                           Qa, Wob, bo, outp, 0);
    } else {
        for (int p = 0; p < 8; ++p) {
            u16* Va = (u16*)d_out + (size_t)p * 2 * XSLICE;
            hipLaunchKernelGGL(f32_to_bf16, dim3(4096), dim3(256), 0, stream,
                               X + (size_t)p * XSLICE, Xb, (int)XSLICE);
            hipLaunchKernelGGL(qkv8, dim3(192), dim3(512), 0, stream,
                               Xb - (size_t)p * XSLICE, Wqt, Wkt, Wvb,
                               biasq, biask, bv, zbuf, Qa, Ka, Va, p);
            hipLaunchKernelGGL(attn_kernel, dim3(8, 128, 1), dim3(256), 0, stream,
                               Qa, Ka, Va, Qa);
            hipLaunchKernelGGL(proj_gemm, dim3(4, 64), dim3(256), 0, stream,
                               Qa, Wob, bo, outp, p);
        }
    }
}